// Round 12
// baseline (1690.395 us; speedup 1.0000x reference)
//
#include <hip/hip_runtime.h>
#include <hip/hip_bf16.h>
#include <stdint.h>
#include <stddef.h>

typedef __bf16 bf16_t;
typedef __attribute__((ext_vector_type(8))) __bf16 bf16x8;
typedef __attribute__((ext_vector_type(4))) float f32x4;
typedef __attribute__((ext_vector_type(16))) float f32x16;
typedef __attribute__((ext_vector_type(4))) uint32_t u32x4;

#define D_MODEL 4096
#define SEQ 1024
#define NH 32
#define HD 128
#define MTOT 2048 /* B*S */

#define VMCNT(n) asm volatile("s_waitcnt vmcnt(" #n ")" ::: "memory")
#define LGKM0() asm volatile("s_waitcnt lgkmcnt(0)" ::: "memory")
#define SCHED0() __builtin_amdgcn_sched_barrier(0)

__device__ __forceinline__ void gload_lds16(const void* g, void* l) {
  __builtin_amdgcn_global_load_lds((const __attribute__((address_space(1))) uint32_t*)g,
                                   (__attribute__((address_space(3))) uint32_t*)l, 16, 0, 0);
}

__device__ __forceinline__ uint32_t cvtpk(float lo, float hi) {
  uint32_t r;
  asm("v_cvt_pk_bf16_f32 %0, %1, %2" : "=v"(r) : "v"(lo), "v"(hi));
  return r;
}
__device__ __forceinline__ void plswap(uint32_t& a, uint32_t& b) {
  asm volatile("v_permlane32_swap_b32 %0, %1" : "+v"(a), "+v"(b));
}

// Decide input dtype from x's bit patterns (proven round 2).
__global__ void dtype_probe(const uint32_t* __restrict__ x, uint32_t* __restrict__ flag) {
  const int lane = threadIdx.x & 63;
  const uint32_t w = x[lane];
  const uint32_t e = (w >> 7) & 0xFF;
  const bool inband = (e >= 100 && e <= 140);
  const unsigned long long m = __ballot(inband);
  if (lane == 0) *flag = (__popcll(m) >= 32) ? 1u : 0u;  // 1 = bf16, 0 = fp32
}

__global__ __launch_bounds__(256) void conv_bf16(const void* __restrict__ src,
                                                 bf16_t* __restrict__ dst, int n,
                                                 const uint32_t* __restrict__ flag) {
  const int i = (blockIdx.x * 256 + threadIdx.x) * 8;
  if (i >= n) return;
  if (*flag) {
    *(bf16x8*)(dst + i) = *(const bf16x8*)((const bf16_t*)src + i);
  } else {
    const float4 a = *(const float4*)((const float*)src + i);
    const float4 b = *(const float4*)((const float*)src + i + 4);
    bf16x8 v;
    v[0] = (bf16_t)a.x; v[1] = (bf16_t)a.y; v[2] = (bf16_t)a.z; v[3] = (bf16_t)a.w;
    v[4] = (bf16_t)b.x; v[5] = (bf16_t)b.y; v[6] = (bf16_t)b.z; v[7] = (bf16_t)b.w;
    *(bf16x8*)(dst + i) = v;
  }
}

// C[M,N] = A[M,K] * B[N,K]^T — 2-phase deep-pipelined NT GEMM, 16x16x32 core.
// A: bf16 via global_load_lds. B: RAW weights (fp32/bf16 per flag), reg-staged
// with WAVE-CONTIGUOUS slab loads (round-11 fix: instruction j covers a
// contiguous 8KB slab of the tile -> full coalescing), cvt+swizzled ds_write.
// VMCNT(2) drains B(t+1) exactly (only the 2 builtin A-loads stay in flight).
template <int MODE>
__global__ __launch_bounds__(512, 2) void gemm_bt(
    const bf16_t* __restrict__ A, const void* __restrict__ Braw,
    void* __restrict__ dstv, const uint32_t* __restrict__ flagp,
    const bf16_t* __restrict__ fcos, const bf16_t* __restrict__ fsin) {
  __shared__ __align__(16) char smem[3 * 49152];
  const int tid = threadIdx.x;
  const int lane = tid & 63, wid = tid >> 6;
  const int fr = lane & 15, fq = lane >> 4;
  const int wm = wid >> 2, wn = wid & 3;
  const int bm0 = blockIdx.x * 128, bn0 = blockIdx.y * 256;
  const bool isbf = (*flagp != 0);

  auto stageA = [&](int t, int bi) {
    const int k0 = t * 64;
    char* ab = smem + bi * 49152;
#pragma unroll
    for (int p = 0; p < 2; ++p) {
      const int o = p * 8192 + tid * 16;
      const int row = o >> 7, ch = (o >> 4) & 7;
      gload_lds16(A + (size_t)(bm0 + row) * D_MODEL + k0 + ((ch ^ (row & 7)) * 8), ab + o);
    }
  };
  // 8 coalesced VMEM loads of B-tile t (each instr = contiguous slab per wave)
  auto issueB = [&](float4 (&st)[8], int t) {
    const int k0 = t * 64;
    if (isbf) {
      const char* bp = (const char*)Braw;
#pragma unroll
      for (int j = 0; j < 8; ++j) {
        const int o = j * 4096 + tid * 8;        // byte off in 32KB bf16 tile
        const int row = o >> 7, colb = o & 127;  // 128B rows
        const uint2 v = *(const uint2*)(bp + ((size_t)(bn0 + row) * D_MODEL + k0) * 2 + colb);
        st[j].x = __uint_as_float(v.x);
        st[j].y = __uint_as_float(v.y);
      }
    } else {
      const char* bp = (const char*)Braw;
#pragma unroll
      for (int j = 0; j < 8; ++j) {
        const int o = j * 8192 + tid * 16;       // byte off in 64KB fp32 tile
        const int row = o >> 8, colb = o & 255;  // 256B rows
        st[j] = *(const float4*)(bp + ((size_t)(bn0 + row) * D_MODEL + k0) * 4 + colb);
      }
    }
  };
  // cvt (if fp32) + swizzled 8B ds_write into buffer bi (chunk-XOR involution)
  auto writeB = [&](float4 (&st)[8], int bi) {
    char* bb = smem + bi * 49152 + 16384;
    if (isbf) {
#pragma unroll
      for (int j = 0; j < 8; ++j) {
        const int o = j * 4096 + tid * 8;
        const int row = o >> 7, colb = o & 127;
        const int ch = colb >> 4, sub = colb & 15;
        const uint2 v{__float_as_uint(st[j].x), __float_as_uint(st[j].y)};
        *(uint2*)(bb + row * 128 + ((ch ^ (row & 7)) << 4) + sub) = v;
      }
    } else {
#pragma unroll
      for (int j = 0; j < 8; ++j) {
        const int o = j * 8192 + tid * 16;
        const int row = o >> 8, colb16 = (o & 255) >> 1;
        const int ch = colb16 >> 4, sub = colb16 & 15;
        const uint2 v{cvtpk(st[j].x, st[j].y), cvtpk(st[j].z, st[j].w)};
        *(uint2*)(bb + row * 128 + ((ch ^ (row & 7)) << 4) + sub) = v;
      }
    }
  };

  f32x4 acc[4][4];
#pragma unroll
  for (int m = 0; m < 4; m++)
#pragma unroll
    for (int n = 0; n < 4; n++) acc[m][n] = f32x4{0.f, 0.f, 0.f, 0.f};

  auto phase = [&](int bi, int kk, bool doA, int tA, int biA) {
    const char* ab = smem + bi * 49152;
    const char* bb = ab + 16384;
    const int swz = ((kk * 4 + fq) ^ (fr & 7)) << 4;
    bf16x8 af[4], bfv[4];
#pragma unroll
    for (int m = 0; m < 4; ++m)
      af[m] = *(const bf16x8*)(ab + (wm * 64 + m * 16 + fr) * 128 + swz);
#pragma unroll
    for (int n = 0; n < 4; ++n)
      bfv[n] = *(const bf16x8*)(bb + (wn * 64 + n * 16 + fr) * 128 + swz);
    if (doA) stageA(tA, biA);
    __builtin_amdgcn_s_barrier();
    LGKM0();
    SCHED0();
    __builtin_amdgcn_s_setprio(1);
#pragma unroll
    for (int m = 0; m < 4; ++m)
#pragma unroll
      for (int n = 0; n < 4; ++n)
        acc[m][n] = __builtin_amdgcn_mfma_f32_16x16x32_bf16(af[m], bfv[n], acc[m][n], 0, 0, 0);
    __builtin_amdgcn_s_setprio(0);
  };

  const int NT = D_MODEL / 64;  // 64
  float4 rA[8], rB[8];
  stageA(0, 0);
  issueB(rA, 0);
  VMCNT(0);
  writeB(rA, 0);
  stageA(1, 1);
  issueB(rA, 1);
  LGKM0();
  __builtin_amdgcn_s_barrier();
  int cur = 0, nxt = 2;
  for (int tt = 0; tt < NT - 2; tt += 2) {
    {  // even tile: pending rA = B(t+1); issue rB = B(t+2)
      phase(cur, 0, true, tt + 2, nxt);
      __builtin_amdgcn_s_barrier();
      phase(cur, 1, false, 0, 0);
      VMCNT(2);
      issueB(rB, tt + 2);
      writeB(rA, (cur == 2) ? 0 : cur + 1);
      LGKM0();
      __builtin_amdgcn_s_barrier();
      cur = (cur == 2) ? 0 : cur + 1;
      nxt = (nxt == 2) ? 0 : nxt + 1;
    }
    {  // odd tile: pending rB; issue rA
      phase(cur, 0, true, tt + 3, nxt);
      __builtin_amdgcn_s_barrier();
      phase(cur, 1, false, 0, 0);
      VMCNT(2);
      issueB(rA, tt + 3);
      writeB(rB, (cur == 2) ? 0 : cur + 1);
      LGKM0();
      __builtin_amdgcn_s_barrier();
      cur = (cur == 2) ? 0 : cur + 1;
      nxt = (nxt == 2) ? 0 : nxt + 1;
    }
  }
  phase(cur, 0, false, 0, 0);
  __builtin_amdgcn_s_barrier();
  phase(cur, 1, false, 0, 0);
  VMCNT(0);
  writeB(rA, (cur == 2) ? 0 : cur + 1);
  LGKM0();
  __builtin_amdgcn_s_barrier();
  cur = (cur == 2) ? 0 : cur + 1;
  phase(cur, 0, false, 0, 0);
  __builtin_amdgcn_s_barrier();
  phase(cur, 1, false, 0, 0);

#pragma unroll
  for (int m = 0; m < 4; m++) {
#pragma unroll
    for (int n = 0; n < 4; n++) {
      const int gn = bn0 + wn * 64 + n * 16 + fr;
#pragma unroll
      for (int r = 0; r < 4; r++) {
        const int gm = bm0 + wm * 64 + m * 16 + fq * 4 + r;
        const float vv = acc[m][n][r];
        if constexpr (MODE == 0) {
          const float pv = __shfl_xor(vv, 1);
          const int s = gm & (SEQ - 1);
          const int i = (gn & (HD - 1)) >> 1;
          const float c = (float)fcos[s * 64 + i];
          const float si = (float)fsin[s * 64 + i];
          const float outv = (gn & 1) ? (pv * si + vv * c) : (vv * c - pv * si);
          const int b = gm >> 10, h = gn >> 7, dd = gn & (HD - 1);
          ((bf16_t*)dstv)[((size_t)(b * NH + h) * SEQ + s) * HD + dd] = (bf16_t)outv;
        } else if constexpr (MODE == 1) {
          const int b = gm >> 10, s = gm & (SEQ - 1), h = gn >> 7, dd = gn & (HD - 1);
          ((bf16_t*)dstv)[((size_t)(b * NH + h) * HD + dd) * SEQ + s] = (bf16_t)vv;
        } else {
          if (isbf) ((bf16_t*)dstv)[(size_t)gm * D_MODEL + gn] = (bf16_t)vv;
          else      ((float*)dstv)[(size_t)gm * D_MODEL + gn] = vv;
        }
      }
    }
  }
}

// Flash attention v3 (round-6, proven): 8 waves x 32 q, KVB=64, 32x32x16,
// swapped QK^T, transposed PV, T12 P-redistribution.
__global__ __launch_bounds__(512, 2) void attn_fwd(
    const bf16_t* __restrict__ Q, const bf16_t* __restrict__ K,
    const bf16_t* __restrict__ V, bf16_t* __restrict__ Out) {
  constexpr float SC = 0.088388347648318447f;
  constexpr float MNEG = -10000.0f;
  __shared__ __align__(16) char smem[65536];
  const int tid = threadIdx.x, lane = tid & 63, wid = tid >> 6;
  const int l31 = lane & 31, hi = lane >> 5, l7 = lane & 7;
  const int qt = 3 - (int)blockIdx.x;
  const int bh = blockIdx.y;
  const int qb0 = qt * 256;
  const int q0w = qb0 + wid * 32;
  const int nt = qt * 4 + 4;

  const bf16_t* Kbase = K + (size_t)bh * SEQ * HD;
  const bf16_t* Vbase = V + (size_t)bh * HD * SEQ;

  bf16x8 qa[8];
  {
    const bf16_t* qp = Q + ((size_t)bh * SEQ + q0w + l31) * HD + hi * 8;
#pragma unroll
    for (int ks = 0; ks < 8; ++ks) qa[ks] = *(const bf16x8*)(qp + ks * 16);
  }

  auto stage = [&](int t, int bi) {
    const int kv0 = t * 64;
#pragma unroll
    for (int pass = 0; pass < 2; ++pass) {
      const int o = pass * 8192 + tid * 16;
      {
        const int row = o >> 8, ch = (o & 255) >> 4;
        gload_lds16(Kbase + (size_t)(kv0 + row) * HD + ((ch ^ (row & 7)) * 8),
                    smem + bi * 16384 + o);
      }
      {
        const int row = o >> 7, ch = (o & 127) >> 4;
        gload_lds16(Vbase + (size_t)row * SEQ + kv0 + ((ch ^ (row & 7)) * 8),
                    smem + 32768 + bi * 16384 + o);
      }
    }
  };

  f32x16 Oacc[4];
#pragma unroll
  for (int i = 0; i < 4; ++i)
#pragma unroll
    for (int j = 0; j < 16; ++j) Oacc[i][j] = 0.f;
  float mrow = MNEG, lrow = 0.f;

  stage(0, 0);
  stage(1, 1);
  VMCNT(4);
  __builtin_amdgcn_s_barrier();

  for (int t = 0; t < nt; ++t) {
    const int kv0 = t * 64;
    if (kv0 < q0w + 32) {
      const char* kb_ = smem + (t & 1) * 16384;
      const char* vb_ = smem + 32768 + (t & 1) * 16384;

      f32x16 sacc[2];
#pragma unroll
      for (int kb = 0; kb < 2; ++kb)
#pragma unroll
        for (int j = 0; j < 16; ++j) sacc[kb][j] = 0.f;
      __builtin_amdgcn_s_setprio(1);
#pragma unroll
      for (int kb = 0; kb < 2; ++kb)
#pragma unroll
        for (int ks = 0; ks < 8; ++ks) {
          bf16x8 kf = *(const bf16x8*)(kb_ + (kb * 32 + l31) * 256 +
                                       (((ks * 2 + hi) ^ l7) << 4));
          sacc[kb] = __builtin_amdgcn_mfma_f32_32x32x16_bf16(kf, qa[ks], sacc[kb], 0, 0, 0);
        }
      __builtin_amdgcn_s_setprio(0);

      const bool diag = (kv0 + 63 > q0w);
      float pm = MNEG;
#pragma unroll
      for (int kb = 0; kb < 2; ++kb)
#pragma unroll
        for (int r = 0; r < 16; ++r) {
          float x = sacc[kb][r] * SC;
          if (diag) {
            const int kvpos = kv0 + kb * 32 + (r & 3) + 8 * (r >> 2) + 4 * hi;
            if (kvpos > q0w + l31) x = MNEG;
          }
          sacc[kb][r] = x;
          pm = fmaxf(pm, x);
        }
      pm = fmaxf(pm, __shfl_xor(pm, 32));
      const float mn = fmaxf(mrow, pm);
      const float al = __expf(mrow - mn);
      mrow = mn;
      float ps = 0.f;
#pragma unroll
      for (int kb = 0; kb < 2; ++kb)
#pragma unroll
        for (int r = 0; r < 16; ++r) {
          const float e = __expf(sacc[kb][r] - mn);
          sacc[kb][r] = e;
          ps += e;
        }
      lrow = lrow * al + ps;
#pragma unroll
      for (int db = 0; db < 4; ++db)
#pragma unroll
        for (int j = 0; j < 16; ++j) Oacc[db][j] *= al;

      uint32_t pw[16];
#pragma unroll
      for (int kb = 0; kb < 2; ++kb) {
        const int o8 = kb * 8;
        pw[o8 + 0] = cvtpk(sacc[kb][0], sacc[kb][1]);
        pw[o8 + 1] = cvtpk(sacc[kb][2], sacc[kb][3]);
        pw[o8 + 2] = cvtpk(sacc[kb][4], sacc[kb][5]);
        pw[o8 + 3] = cvtpk(sacc[kb][6], sacc[kb][7]);
        plswap(pw[o8 + 0], pw[o8 + 2]);
        plswap(pw[o8 + 1], pw[o8 + 3]);
        pw[o8 + 4] = cvtpk(sacc[kb][8], sacc[kb][9]);
        pw[o8 + 5] = cvtpk(sacc[kb][10], sacc[kb][11]);
        pw[o8 + 6] = cvtpk(sacc[kb][12], sacc[kb][13]);
        pw[o8 + 7] = cvtpk(sacc[kb][14], sacc[kb][15]);
        plswap(pw[o8 + 4], pw[o8 + 6]);
        plswap(pw[o8 + 5], pw[o8 + 7]);
      }

      __builtin_amdgcn_s_setprio(1);
#pragma unroll
      for (int db = 0; db < 4; ++db)
#pragma unroll
        for (int ks2 = 0; ks2 < 4; ++ks2) {
          bf16x8 vf = *(const bf16x8*)(vb_ + (db * 32 + l31) * 128 +
                                       (((ks2 * 2 + hi) ^ l7) << 4));
          union { u32x4 u; bf16x8 v; } pc;
          pc.u = u32x4{pw[ks2 * 4], pw[ks2 * 4 + 1], pw[ks2 * 4 + 2], pw[ks2 * 4 + 3]};
          Oacc[db] = __builtin_amdgcn_mfma_f32_32x32x16_bf16(vf, pc.v, Oacc[db], 0, 0, 0);
        }
      __builtin_amdgcn_s_setprio(0);
    }

    __builtin_amdgcn_s_barrier();
    if (t + 2 < nt) {
      stage(t + 2, t & 1);
      VMCNT(4);
    } else if (t + 1 < nt) {
      VMCNT(0);
    }
    __builtin_amdgcn_s_barrier();
  }

  lrow += __shfl_xor(lrow, 32);
  const float linv = 1.0f / fmaxf(lrow, 1e-20f);

  {
    char* ob = smem + wid * 8192;
#pragma unroll
    for (int db = 0; db < 4; ++db)
#pragma unroll
      for (int rp = 0; rp < 8; ++rp) {
        const int r = rp * 2;
        const int d = db * 32 + (r & 3) + 8 * (r >> 2) + 4 * hi;
        const uint32_t w = cvtpk(Oacc[db][r] * linv, Oacc[db][r + 1] * linv);
        *(uint32_t*)(ob + l31 * 256 + ((d * 2) ^ ((l31 & 7) << 4))) = w;
      }
  }
  __builtin_amdgcn_s_barrier();
  const int b = bh >> 5, h = bh & 31;
#pragma unroll
  for (int pass = 0; pass < 8; ++pass) {
    const int o = pass * 8192 + tid * 16;
    const int row = o >> 8, ch = (o & 255) >> 4;
    const u32x4 val = *(const u32x4*)(smem + row * 256 + ((ch ^ (row & 7)) << 4));
    *(u32x4*)(Out + ((size_t)(b * SEQ + qb0 + row)) * D_MODEL + h * HD + ch * 8) = val;
  }
}

extern "C" void kernel_launch(void* const* d_in, const int* in_sizes, int n_in,
                              void* d_out, int out_size, void* d_ws, size_t ws_size,
                              hipStream_t stream) {
  (void)in_sizes; (void)n_in; (void)out_size;
  const void* x_raw    = d_in[0];
  const void* fcos_raw = d_in[2];
  const void* fsin_raw = d_in[3];
  const void* wq_raw   = d_in[7];
  const void* wk_raw   = d_in[8];
  const void* wv_raw   = d_in[9];
  const void* wo_raw   = d_in[10];

  const size_t NX = (size_t)MTOT * D_MODEL;
  const size_t NF = SEQ * (HD / 2);

  char* base = (char*)d_ws;
  uint32_t* flag = (uint32_t*)base;
  bf16_t* fc = (bf16_t*)(base + 4096);
  bf16_t* fs = (bf16_t*)(base + 4096 + 131072);
  bf16_t* elems = (bf16_t*)(base + (1 << 20));
  bf16_t* xc = elems;                 // NX
  bf16_t* q_ws = xc + NX;             // NX
  bf16_t* k_ws = q_ws + NX;           // NX
  bf16_t* v_ws = k_ws + NX;           // NX
  bf16_t* a_ws = v_ws + NX;           // NX
  const size_t NEED = (1 << 20) + 2 * (5 * NX);
  if (ws_size < NEED) return;

  dtype_probe<<<1, 64, 0, stream>>>((const uint32_t*)x_raw, flag);

  const int cb_x = (int)(NX / (256 * 8));
  const int cb_f = (int)(NF / (256 * 8));
  conv_bf16<<<cb_x, 256, 0, stream>>>(x_raw, xc, (int)NX, flag);
  conv_bf16<<<cb_f, 256, 0, stream>>>(fcos_raw, fc, (int)NF, flag);
  conv_bf16<<<cb_f, 256, 0, stream>>>(fsin_raw, fs, (int)NF, flag);

  dim3 gg(MTOT / 128, D_MODEL / 256);
  gemm_bt<0><<<gg, 512, 0, stream>>>(xc, wq_raw, q_ws, flag, fc, fs);
  gemm_bt<0><<<gg, 512, 0, stream>>>(xc, wk_raw, k_ws, flag, fc, fs);
  gemm_bt<1><<<gg, 512, 0, stream>>>(xc, wv_raw, v_ws, flag, fc, fs);

  attn_fwd<<<dim3(4, 2 * NH), 512, 0, stream>>>(q_ws, k_ws, v_ws, a_ws);

  gemm_bt<2><<<gg, 512, 0, stream>>>(a_ws, wo_raw, d_out, flag, fc, fs);
}

// Round 13
// 398.789 us; speedup vs baseline: 4.2388x; 4.2388x over previous
//
#include <hip/hip_runtime.h>
#include <hip/hip_bf16.h>
#include <stdint.h>
#include <stddef.h>

typedef __bf16 bf16_t;
typedef __attribute__((ext_vector_type(8))) __bf16 bf16x8;
typedef __attribute__((ext_vector_type(4))) float f32x4;
typedef __attribute__((ext_vector_type(16))) float f32x16;
typedef __attribute__((ext_vector_type(4))) uint32_t u32x4;

#define D_MODEL 4096
#define SEQ 1024
#define NH 32
#define HD 128
#define MTOT 2048 /* B*S */

#define VMCNT(n) asm volatile("s_waitcnt vmcnt(" #n ")" ::: "memory")
#define LGKM0() asm volatile("s_waitcnt lgkmcnt(0)" ::: "memory")
#define SCHED0() __builtin_amdgcn_sched_barrier(0)

__device__ __forceinline__ void gload_lds16(const void* g, void* l) {
  __builtin_amdgcn_global_load_lds((const __attribute__((address_space(1))) uint32_t*)g,
                                   (__attribute__((address_space(3))) uint32_t*)l, 16, 0, 0);
}

__device__ __forceinline__ uint32_t cvtpk(float lo, float hi) {
  uint32_t r;
  asm("v_cvt_pk_bf16_f32 %0, %1, %2" : "=v"(r) : "v"(lo), "v"(hi));
  return r;
}
__device__ __forceinline__ void plswap(uint32_t& a, uint32_t& b) {
  asm volatile("v_permlane32_swap_b32 %0, %1" : "+v"(a), "+v"(b));
}

// Decide input dtype from x's bit patterns (proven round 2).
__global__ void dtype_probe(const uint32_t* __restrict__ x, uint32_t* __restrict__ flag) {
  const int lane = threadIdx.x & 63;
  const uint32_t w = x[lane];
  const uint32_t e = (w >> 7) & 0xFF;
  const bool inband = (e >= 100 && e <= 140);
  const unsigned long long m = __ballot(inband);
  if (lane == 0) *flag = (__popcll(m) >= 32) ? 1u : 0u;  // 1 = bf16, 0 = fp32
}

__global__ __launch_bounds__(256) void conv_bf16(const void* __restrict__ src,
                                                 bf16_t* __restrict__ dst, int n,
                                                 const uint32_t* __restrict__ flag) {
  const int i = (blockIdx.x * 256 + threadIdx.x) * 8;
  if (i >= n) return;
  if (*flag) {
    *(bf16x8*)(dst + i) = *(const bf16x8*)((const bf16_t*)src + i);
  } else {
    const float4 a = *(const float4*)((const float*)src + i);
    const float4 b = *(const float4*)((const float*)src + i + 4);
    bf16x8 v;
    v[0] = (bf16_t)a.x; v[1] = (bf16_t)a.y; v[2] = (bf16_t)a.z; v[3] = (bf16_t)a.w;
    v[4] = (bf16_t)b.x; v[5] = (bf16_t)b.y; v[6] = (bf16_t)b.z; v[7] = (bf16_t)b.w;
    *(bf16x8*)(dst + i) = v;
  }
}

// C[M,N] = A[M,K] * B[N,K]^T — 2-phase deep-pipelined NT GEMM, 16x16x32 core
// (round-9 structure, proven 74.5us/922TF/0-conflict) + XCD supertile swizzle (T1).
// MODE 0: RoPE fused, write (B,H,S,hd). MODE 1: write (B,H,hd,S). MODE 2: row-major.
template <int MODE>
__global__ __launch_bounds__(512, 2) void gemm_bt(
    const bf16_t* __restrict__ A, const bf16_t* __restrict__ B,
    void* __restrict__ dstv, const uint32_t* __restrict__ flagp,
    const bf16_t* __restrict__ fcos, const bf16_t* __restrict__ fsin) {
  __shared__ __align__(16) char smem[3 * 49152];
  const int tid = threadIdx.x;
  const int lane = tid & 63, wid = tid >> 6;
  const int fr = lane & 15, fq = lane >> 4;
  const int wm = wid >> 2, wn = wid & 3;
  // T1: XCD-aware 2-D supertile remap. Grid 16x16 = 16 supertiles of 4x4 blocks;
  // dispatch id d -> XCD d&7 (round-robin assumption; perf-only). XCD k owns
  // supertiles {2k, 2k+1} -> 4 A-panels + 8 B-panels (~12 MB) per XCD L2.
  const int d = (int)(blockIdx.x + gridDim.x * blockIdx.y);
  const int st = ((d & 7) << 1) | ((d >> 3) & 1);
  const int ist = d >> 4;
  const int bxs = (st & 3) * 4 + (ist & 3);
  const int bys = (st >> 2) * 4 + (ist >> 2);
  const int bm0 = bxs * 128, bn0 = bys * 256;
  const bool isbf = (MODE == 2) ? (*flagp != 0) : true;

  auto stage_half = [&](int t, int bi, int h) {
    const int k0 = t * 64;
    char* ab = smem + bi * 49152;
    char* bb = ab + 16384;
    {
      const int o = h * 8192 + tid * 16;
      const int row = o >> 7, ch = (o >> 4) & 7;
      gload_lds16(A + (size_t)(bm0 + row) * D_MODEL + k0 + ((ch ^ (row & 7)) * 8), ab + o);
    }
#pragma unroll
    for (int j = 0; j < 2; ++j) {
      const int o = (h * 2 + j) * 8192 + tid * 16;
      const int row = o >> 7, ch = (o >> 4) & 7;
      gload_lds16(B + (size_t)(bn0 + row) * D_MODEL + k0 + ((ch ^ (row & 7)) * 8), bb + o);
    }
  };

  f32x4 acc[4][4];
#pragma unroll
  for (int m = 0; m < 4; m++)
#pragma unroll
    for (int n = 0; n < 4; n++) acc[m][n] = f32x4{0.f, 0.f, 0.f, 0.f};

  auto phase = [&](int bi, int kk, bool do_stage, int ts, int bs, int h) {
    const char* ab = smem + bi * 49152;
    const char* bb = ab + 16384;
    const int swz = ((kk * 4 + fq) ^ (fr & 7)) << 4;
    bf16x8 af[4], bfv[4];
#pragma unroll
    for (int m = 0; m < 4; ++m)
      af[m] = *(const bf16x8*)(ab + (wm * 64 + m * 16 + fr) * 128 + swz);
#pragma unroll
    for (int n = 0; n < 4; ++n)
      bfv[n] = *(const bf16x8*)(bb + (wn * 64 + n * 16 + fr) * 128 + swz);
    if (do_stage) stage_half(ts, bs, h);
    __builtin_amdgcn_s_barrier();
    LGKM0();
    SCHED0();
    __builtin_amdgcn_s_setprio(1);
#pragma unroll
    for (int m = 0; m < 4; ++m)
#pragma unroll
      for (int n = 0; n < 4; ++n)
        acc[m][n] = __builtin_amdgcn_mfma_f32_16x16x32_bf16(af[m], bfv[n], acc[m][n], 0, 0, 0);
    __builtin_amdgcn_s_setprio(0);
  };

  const int NT = D_MODEL / 64;
  stage_half(0, 0, 0); stage_half(0, 0, 1);
  stage_half(1, 1, 0); stage_half(1, 1, 1);
  VMCNT(6);
  __builtin_amdgcn_s_barrier();
  SCHED0();
  int cur = 0, nxt = 2;
  for (int t = 0; t < NT - 2; ++t) {
    phase(cur, 0, true, t + 2, nxt, 0);
    __builtin_amdgcn_s_barrier();
    phase(cur, 1, true, t + 2, nxt, 1);
    VMCNT(6);
    __builtin_amdgcn_s_barrier();
    SCHED0();
    cur = (cur == 2) ? 0 : cur + 1;
    nxt = (nxt == 2) ? 0 : nxt + 1;
  }
  phase(cur, 0, false, 0, 0, 0);
  __builtin_amdgcn_s_barrier();
  phase(cur, 1, false, 0, 0, 0);
  VMCNT(0);
  __builtin_amdgcn_s_barrier();
  SCHED0();
  cur = (cur == 2) ? 0 : cur + 1;
  phase(cur, 0, false, 0, 0, 0);
  __builtin_amdgcn_s_barrier();
  phase(cur, 1, false, 0, 0, 0);

#pragma unroll
  for (int m = 0; m < 4; m++) {
#pragma unroll
    for (int n = 0; n < 4; n++) {
      const int gn = bn0 + wn * 64 + n * 16 + fr;
#pragma unroll
      for (int r = 0; r < 4; r++) {
        const int gm = bm0 + wm * 64 + m * 16 + fq * 4 + r;
        const float vv = acc[m][n][r];
        if constexpr (MODE == 0) {
          // fused RoPE: partner col gn^1 lives in lane^1, same (m,n,r)
          const float pv = __shfl_xor(vv, 1);
          const int s = gm & (SEQ - 1);
          const int i = (gn & (HD - 1)) >> 1;
          const float c = (float)fcos[s * 64 + i];
          const float si = (float)fsin[s * 64 + i];
          const float outv = (gn & 1) ? (pv * si + vv * c) : (vv * c - pv * si);
          const int b = gm >> 10, h = gn >> 7, dd = gn & (HD - 1);
          ((bf16_t*)dstv)[((size_t)(b * NH + h) * SEQ + s) * HD + dd] = (bf16_t)outv;
        } else if constexpr (MODE == 1) {
          const int b = gm >> 10, s = gm & (SEQ - 1), h = gn >> 7, dd = gn & (HD - 1);
          ((bf16_t*)dstv)[((size_t)(b * NH + h) * HD + dd) * SEQ + s] = (bf16_t)vv;
        } else {
          if (isbf) ((bf16_t*)dstv)[(size_t)gm * D_MODEL + gn] = (bf16_t)vv;
          else      ((float*)dstv)[(size_t)gm * D_MODEL + gn] = vv;
        }
      }
    }
  }
}

// Flash attention v3 (round-6, proven): 8 waves x 32 q, KVB=64, 32x32x16,
// swapped QK^T, transposed PV, T12 P-redistribution.
__global__ __launch_bounds__(512, 2) void attn_fwd(
    const bf16_t* __restrict__ Q, const bf16_t* __restrict__ K,
    const bf16_t* __restrict__ V, bf16_t* __restrict__ Out) {
  constexpr float SC = 0.088388347648318447f;
  constexpr float MNEG = -10000.0f;
  __shared__ __align__(16) char smem[65536];
  const int tid = threadIdx.x, lane = tid & 63, wid = tid >> 6;
  const int l31 = lane & 31, hi = lane >> 5, l7 = lane & 7;
  const int qt = 3 - (int)blockIdx.x;
  const int bh = blockIdx.y;
  const int qb0 = qt * 256;
  const int q0w = qb0 + wid * 32;
  const int nt = qt * 4 + 4;

  const bf16_t* Kbase = K + (size_t)bh * SEQ * HD;
  const bf16_t* Vbase = V + (size_t)bh * HD * SEQ;

  bf16x8 qa[8];
  {
    const bf16_t* qp = Q + ((size_t)bh * SEQ + q0w + l31) * HD + hi * 8;
#pragma unroll
    for (int ks = 0; ks < 8; ++ks) qa[ks] = *(const bf16x8*)(qp + ks * 16);
  }

  auto stage = [&](int t, int bi) {
    const int kv0 = t * 64;
#pragma unroll
    for (int pass = 0; pass < 2; ++pass) {
      const int o = pass * 8192 + tid * 16;
      {
        const int row = o >> 8, ch = (o & 255) >> 4;
        gload_lds16(Kbase + (size_t)(kv0 + row) * HD + ((ch ^ (row & 7)) * 8),
                    smem + bi * 16384 + o);
      }
      {
        const int row = o >> 7, ch = (o & 127) >> 4;
        gload_lds16(Vbase + (size_t)row * SEQ + kv0 + ((ch ^ (row & 7)) * 8),
                    smem + 32768 + bi * 16384 + o);
      }
    }
  };

  f32x16 Oacc[4];
#pragma unroll
  for (int i = 0; i < 4; ++i)
#pragma unroll
    for (int j = 0; j < 16; ++j) Oacc[i][j] = 0.f;
  float mrow = MNEG, lrow = 0.f;

  stage(0, 0);
  stage(1, 1);
  VMCNT(4);
  __builtin_amdgcn_s_barrier();

  for (int t = 0; t < nt; ++t) {
    const int kv0 = t * 64;
    if (kv0 < q0w + 32) {
      const char* kb_ = smem + (t & 1) * 16384;
      const char* vb_ = smem + 32768 + (t & 1) * 16384;

      f32x16 sacc[2];
#pragma unroll
      for (int kb = 0; kb < 2; ++kb)
#pragma unroll
        for (int j = 0; j < 16; ++j) sacc[kb][j] = 0.f;
      __builtin_amdgcn_s_setprio(1);
#pragma unroll
      for (int kb = 0; kb < 2; ++kb)
#pragma unroll
        for (int ks = 0; ks < 8; ++ks) {
          bf16x8 kf = *(const bf16x8*)(kb_ + (kb * 32 + l31) * 256 +
                                       (((ks * 2 + hi) ^ l7) << 4));
          sacc[kb] = __builtin_amdgcn_mfma_f32_32x32x16_bf16(kf, qa[ks], sacc[kb], 0, 0, 0);
        }
      __builtin_amdgcn_s_setprio(0);

      const bool diag = (kv0 + 63 > q0w);
      float pm = MNEG;
#pragma unroll
      for (int kb = 0; kb < 2; ++kb)
#pragma unroll
        for (int r = 0; r < 16; ++r) {
          float x = sacc[kb][r] * SC;
          if (diag) {
            const int kvpos = kv0 + kb * 32 + (r & 3) + 8 * (r >> 2) + 4 * hi;
            if (kvpos > q0w + l31) x = MNEG;
          }
          sacc[kb][r] = x;
          pm = fmaxf(pm, x);
        }
      pm = fmaxf(pm, __shfl_xor(pm, 32));
      const float mn = fmaxf(mrow, pm);
      const float al = __expf(mrow - mn);
      mrow = mn;
      float ps = 0.f;
#pragma unroll
      for (int kb = 0; kb < 2; ++kb)
#pragma unroll
        for (int r = 0; r < 16; ++r) {
          const float e = __expf(sacc[kb][r] - mn);
          sacc[kb][r] = e;
          ps += e;
        }
      lrow = lrow * al + ps;
#pragma unroll
      for (int db = 0; db < 4; ++db)
#pragma unroll
        for (int j = 0; j < 16; ++j) Oacc[db][j] *= al;

      uint32_t pw[16];
#pragma unroll
      for (int kb = 0; kb < 2; ++kb) {
        const int o8 = kb * 8;
        pw[o8 + 0] = cvtpk(sacc[kb][0], sacc[kb][1]);
        pw[o8 + 1] = cvtpk(sacc[kb][2], sacc[kb][3]);
        pw[o8 + 2] = cvtpk(sacc[kb][4], sacc[kb][5]);
        pw[o8 + 3] = cvtpk(sacc[kb][6], sacc[kb][7]);
        plswap(pw[o8 + 0], pw[o8 + 2]);
        plswap(pw[o8 + 1], pw[o8 + 3]);
        pw[o8 + 4] = cvtpk(sacc[kb][8], sacc[kb][9]);
        pw[o8 + 5] = cvtpk(sacc[kb][10], sacc[kb][11]);
        pw[o8 + 6] = cvtpk(sacc[kb][12], sacc[kb][13]);
        pw[o8 + 7] = cvtpk(sacc[kb][14], sacc[kb][15]);
        plswap(pw[o8 + 4], pw[o8 + 6]);
        plswap(pw[o8 + 5], pw[o8 + 7]);
      }

      __builtin_amdgcn_s_setprio(1);
#pragma unroll
      for (int db = 0; db < 4; ++db)
#pragma unroll
        for (int ks2 = 0; ks2 < 4; ++ks2) {
          bf16x8 vf = *(const bf16x8*)(vb_ + (db * 32 + l31) * 128 +
                                       (((ks2 * 2 + hi) ^ l7) << 4));
          union { u32x4 u; bf16x8 v; } pc;
          pc.u = u32x4{pw[ks2 * 4], pw[ks2 * 4 + 1], pw[ks2 * 4 + 2], pw[ks2 * 4 + 3]};
          Oacc[db] = __builtin_amdgcn_mfma_f32_32x32x16_bf16(vf, pc.v, Oacc[db], 0, 0, 0);
        }
      __builtin_amdgcn_s_setprio(0);
    }

    __builtin_amdgcn_s_barrier();
    if (t + 2 < nt) {
      stage(t + 2, t & 1);
      VMCNT(4);
    } else if (t + 1 < nt) {
      VMCNT(0);
    }
    __builtin_amdgcn_s_barrier();
  }

  lrow += __shfl_xor(lrow, 32);
  const float linv = 1.0f / fmaxf(lrow, 1e-20f);

  {
    char* ob = smem + wid * 8192;
#pragma unroll
    for (int db = 0; db < 4; ++db)
#pragma unroll
      for (int rp = 0; rp < 8; ++rp) {
        const int r = rp * 2;
        const int d = db * 32 + (r & 3) + 8 * (r >> 2) + 4 * hi;
        const uint32_t w = cvtpk(Oacc[db][r] * linv, Oacc[db][r + 1] * linv);
        *(uint32_t*)(ob + l31 * 256 + ((d * 2) ^ ((l31 & 7) << 4))) = w;
      }
  }
  __builtin_amdgcn_s_barrier();
  const int b = bh >> 5, h = bh & 31;
#pragma unroll
  for (int pass = 0; pass < 8; ++pass) {
    const int o = pass * 8192 + tid * 16;
    const int row = o >> 8, ch = (o & 255) >> 4;
    const u32x4 val = *(const u32x4*)(smem + row * 256 + ((ch ^ (row & 7)) << 4));
    *(u32x4*)(Out + ((size_t)(b * SEQ + qb0 + row)) * D_MODEL + h * HD + ch * 8) = val;
  }
}

extern "C" void kernel_launch(void* const* d_in, const int* in_sizes, int n_in,
                              void* d_out, int out_size, void* d_ws, size_t ws_size,
                              hipStream_t stream) {
  (void)in_sizes; (void)n_in; (void)out_size;
  const void* x_raw    = d_in[0];
  const void* fcos_raw = d_in[2];
  const void* fsin_raw = d_in[3];
  const void* wq_raw   = d_in[7];
  const void* wk_raw   = d_in[8];
  const void* wv_raw   = d_in[9];
  const void* wo_raw   = d_in[10];

  const size_t NX = (size_t)MTOT * D_MODEL;
  const size_t NW = (size_t)D_MODEL * D_MODEL;
  const size_t NF = SEQ * (HD / 2);

  char* base = (char*)d_ws;
  uint32_t* flag = (uint32_t*)base;
  bf16_t* fc = (bf16_t*)(base + 4096);
  bf16_t* fs = (bf16_t*)(base + 4096 + 131072);
  bf16_t* elems = (bf16_t*)(base + (1 << 20));
  bf16_t* xc = elems;
  bf16_t* w0 = xc + NX;
  bf16_t* w1 = w0 + NW;
  bf16_t* q_ws = w1 + NW;
  bf16_t* k_ws = q_ws + NX;
  bf16_t* v_ws = k_ws + NX;
  bf16_t* a_ws = v_ws + NX;
  const size_t NEED = (1 << 20) + 2 * (5 * NX + 2 * NW);
  if (ws_size < NEED) return;

  dtype_probe<<<1, 64, 0, stream>>>((const uint32_t*)x_raw, flag);

  const int cb_x = (int)(NX / (256 * 8));
  const int cb_w = (int)(NW / (256 * 8));
  const int cb_f = (int)(NF / (256 * 8));
  conv_bf16<<<cb_x, 256, 0, stream>>>(x_raw, xc, (int)NX, flag);
  conv_bf16<<<cb_f, 256, 0, stream>>>(fcos_raw, fc, (int)NF, flag);
  conv_bf16<<<cb_f, 256, 0, stream>>>(fsin_raw, fs, (int)NF, flag);

  dim3 gg(MTOT / 128, D_MODEL / 256);
  conv_bf16<<<cb_w, 256, 0, stream>>>(wq_raw, w0, (int)NW, flag);
  gemm_bt<0><<<gg, 512, 0, stream>>>(xc, w0, q_ws, flag, fc, fs);
  conv_bf16<<<cb_w, 256, 0, stream>>>(wk_raw, w1, (int)NW, flag);
  gemm_bt<0><<<gg, 512, 0, stream>>>(xc, w1, k_ws, flag, fc, fs);
  conv_bf16<<<cb_w, 256, 0, stream>>>(wv_raw, w0, (int)NW, flag);
  gemm_bt<1><<<gg, 512, 0, stream>>>(xc, w0, v_ws, flag, fc, fs);

  attn_fwd<<<dim3(4, 2 * NH), 512, 0, stream>>>(q_ws, k_ws, v_ws, a_ws);

  conv_bf16<<<cb_w, 256, 0, stream>>>(wo_raw, w1, (int)NW, flag);
  gemm_bt<2><<<gg, 512, 0, stream>>>(a_ws, w1, d_out, flag, fc, fs);
}